// Round 4
// baseline (117.593 us; speedup 1.0000x reference)
//
#include <hip/hip_runtime.h>
#include <hip/hip_bf16.h>

// Problem constants (reference: Ex/Ey [8192,256] f32, out [8192] f32)
#define NROWS 8192
#define DDIM  256
#define TILE  128
#define BK    64
#define NRND  4        // DDIM / BK

typedef __bf16 bf16x8 __attribute__((ext_vector_type(8)));
typedef __bf16 bf16x4 __attribute__((ext_vector_type(4)));
typedef float  f32x4  __attribute__((ext_vector_type(4)));

// exp(LOG_NORM - 0.5*((c-1)/0.05)^2) = exp2(-K*c^2 + 2K*c + (L - K))
// K = 200/ln2 = 288.53900818, L = LOG_NORM/ln2 = 2.99618003
#define PA  -288.53900818f
#define PB   577.07801636f
#define PC  -285.54282815f

// Wave-per-row normalize for BOTH matrices; blocks 0..7 also zero d_out.
__global__ __launch_bounds__(256) void normalize2(
    const float* __restrict__ Ex, const float* __restrict__ Ey,
    __hip_bfloat16* __restrict__ Xn, __hip_bfloat16* __restrict__ Yn,
    float* __restrict__ out) {
    const int tid  = threadIdx.x;
    const int wave = tid >> 6;
    const int lane = tid & 63;
    const int gr   = blockIdx.x * 4 + wave;        // 0..16383

    if (blockIdx.x < 8) {                          // zero 8192 floats of out
        f32x4 z = {0.f, 0.f, 0.f, 0.f};
        ((f32x4*)out)[blockIdx.x * 256 + tid] = z;
    }

    const float* src; __hip_bfloat16* dst; int row;
    if (gr < NROWS) { src = Ex; dst = Xn; row = gr; }
    else            { src = Ey; dst = Yn; row = gr - NROWS; }

    const float4 v = *(const float4*)(src + (size_t)row * DDIM + lane * 4);
    float ss = v.x * v.x + v.y * v.y + v.z * v.z + v.w * v.w;
#pragma unroll
    for (int o = 32; o > 0; o >>= 1) ss += __shfl_xor(ss, o);
    const float inv = 1.0f / fmaxf(sqrtf(ss), 1e-8f);
    bf16x4 o4;
    o4[0] = (__bf16)(v.x * inv);
    o4[1] = (__bf16)(v.y * inv);
    o4[2] = (__bf16)(v.z * inv);
    o4[3] = (__bf16)(v.w * inv);
    *(bf16x4*)((__bf16*)dst + (size_t)row * DDIM + lane * 4) = o4;
}

__device__ inline void async_load16(const void* g, void* l) {
    __builtin_amdgcn_global_load_lds(
        (const __attribute__((address_space(1))) unsigned int*)g,
        (__attribute__((address_space(3))) unsigned int*)l, 16, 0, 0);
}

// C = Xn * Yn^T fused with gaussian + column-sum.
// 128x128 tile, 4 waves 2x2, wave tile 64x64 (4x4 frags), BK=64.
// LDS DOUBLE-BUFFERED: round r+1's global_load_lds issued right after the
// barrier of round r, so the vmcnt(0) drain at the next barrier lands after
// a full compute round.  k-chunks XOR-swizzled by (row&7) -> 0 conflicts (R1).
__global__ __launch_bounds__(256, 2) void cosgauss_gemm(
    const __hip_bfloat16* __restrict__ Xn,
    const __hip_bfloat16* __restrict__ Yn,
    float* __restrict__ out) {
    __shared__ __hip_bfloat16 As[2][TILE * BK];   // 2 x 16 KB
    __shared__ __hip_bfloat16 Bs[2][TILE * BK];   // 2 x 16 KB
    __shared__ float colpart[TILE];

    const int tid  = threadIdx.x;
    const int lane = tid & 63;
    const int w    = tid >> 6;       // wave 0..3
    const int wr   = w >> 1;         // wave row 0..1 (64 rows each)
    const int wc   = w & 1;          // wave col 0..1 (64 cols each)
    const int rowBase = blockIdx.y * TILE;
    const int colBase = blockIdx.x * TILE;

    const __hip_bfloat16* Ag = Xn + (size_t)rowBase * DDIM;
    const __hip_bfloat16* Bg = Yn + (size_t)colBase * DDIM;

    f32x4 acc[4][4] = {};

    const int lr  = lane >> 3;                // staging: row within 8-row chunk
    const int cbS = ((lane & 7) ^ lr) * 8;    // staging: SWIZZLED global k offset
    const int lm  = lane & 15;                // mfma: m (A) / n (B) index
    const int kq  = lane >> 4;                // mfma: k-quad
    const int sw  = lm & 7;                   // read-side swizzle key (= row&7)

    // stage round `r` into buffer `buf`
    auto stage = [&](int r, int buf) {
        const int kt = r * BK;
#pragma unroll
        for (int j = 0; j < 4; ++j) {
            const int chunk = w * 4 + j;            // 0..15 (8 rows each)
            const int rr = chunk * 8 + lr;
            async_load16(Ag + (size_t)rr * DDIM + kt + cbS,
                         (char*)As[buf] + chunk * 1024);
            async_load16(Bg + (size_t)rr * DDIM + kt + cbS,
                         (char*)Bs[buf] + chunk * 1024);
        }
    };

    stage(0, 0);   // prologue: first round in flight

#pragma unroll
    for (int r = 0; r < NRND; ++r) {
        const int buf = r & 1;
        __syncthreads();             // drains round r's loads; guards buf reuse
        if (r + 1 < NRND) stage(r + 1, buf ^ 1);

        const __bf16* Ap = (const __bf16*)As[buf];
        const __bf16* Bp = (const __bf16*)Bs[buf];
#pragma unroll
        for (int kk = 0; kk < BK; kk += 32) {
            const int kco = ((kk >> 3) + kq) ^ sw;   // swizzled k-chunk index
            bf16x8 a[4], b[4];
#pragma unroll
            for (int rf = 0; rf < 4; ++rf)
                a[rf] = *(const bf16x8*)(Ap + (wr * 64 + rf * 16 + lm) * BK + kco * 8);
#pragma unroll
            for (int cf = 0; cf < 4; ++cf)
                b[cf] = *(const bf16x8*)(Bp + (wc * 64 + cf * 16 + lm) * BK + kco * 8);
#pragma unroll
            for (int rf = 0; rf < 4; ++rf)
#pragma unroll
                for (int cf = 0; cf < 4; ++cf)
                    acc[rf][cf] = __builtin_amdgcn_mfma_f32_16x16x32_bf16(
                        a[rf], b[cf], acc[rf][cf], 0, 0, 0);
        }
    }

    // Epilogue: gaussian (Horner: 2 fma + exp2) + column sums.
    // C/D layout: col = lane&15, row = (lane>>4)*4 + reg  [m89/m91 verified]
    float s[4];
#pragma unroll
    for (int cf = 0; cf < 4; ++cf) {
        float t = 0.0f;
#pragma unroll
        for (int rf = 0; rf < 4; ++rf) {
#pragma unroll
            for (int i = 0; i < 4; ++i) {
                const float c = acc[rf][cf][i];
                t += exp2f(fmaf(c, fmaf(c, PA, PB), PC));
            }
        }
        t += __shfl_xor(t, 16);      // reduce over the 4 quads (rows)
        t += __shfl_xor(t, 32);
        s[cf] = t;
    }
    const float v = (lane < 16) ? s[0] : (lane < 32) ? s[1] : (lane < 48) ? s[2] : s[3];
    const int c = wc * 64 + lane;    // 0..127 within tile
    if (wr == 0) colpart[c] = v;
    __syncthreads();
    if (wr == 1) atomicAdd(&out[colBase + c], v + colpart[c]);
}

extern "C" void kernel_launch(void* const* d_in, const int* in_sizes, int n_in,
                              void* d_out, int out_size, void* d_ws, size_t ws_size,
                              hipStream_t stream) {
    const float* Ex = (const float*)d_in[0];
    const float* Ey = (const float*)d_in[1];
    float* out = (float*)d_out;

    __hip_bfloat16* Xn = (__hip_bfloat16*)d_ws;                    // 4 MB
    __hip_bfloat16* Yn = Xn + (size_t)NROWS * DDIM;                // +4 MB

    normalize2<<<(2 * NROWS) / 4, 256, 0, stream>>>(Ex, Ey, Xn, Yn, out);

    dim3 grid(NROWS / TILE, NROWS / TILE);   // 64 x 64 tiles
    cosgauss_gemm<<<grid, 256, 0, stream>>>(Xn, Yn, out);
}

// Round 5
// 89.387 us; speedup vs baseline: 1.3156x; 1.3156x over previous
//
#include <hip/hip_runtime.h>
#include <hip/hip_bf16.h>

// Problem constants (reference: Ex/Ey [8192,256] f32, out [8192] f32)
#define NROWS 8192
#define DDIM  256
#define TILE  128
#define KB    256      // K in bytes per row (fp8) = DDIM

typedef int   i32x4 __attribute__((ext_vector_type(4)));
typedef int   i32x8 __attribute__((ext_vector_type(8)));
typedef float f32x4 __attribute__((ext_vector_type(4)));

// exp(LOG_NORM - 0.5*((c-1)/0.05)^2) = exp2(PA*c^2 + PB*c + PC)
#define PA  -288.53900818f
#define PB   577.07801636f
#define PC  -285.54282815f
// exp2f(x) == 0.0f for x <= -160 (incl. denorm range margin): safe skip bound
#define ZCUT -160.0f

// Wave-per-row normalize -> unit rows quantized to fp8 e4m3 (OCP).
// Blocks 0..7 also zero d_out.
__global__ __launch_bounds__(256) void normalize2(
    const float* __restrict__ Ex, const float* __restrict__ Ey,
    unsigned char* __restrict__ Xn, unsigned char* __restrict__ Yn,
    float* __restrict__ out) {
    const int tid  = threadIdx.x;
    const int wave = tid >> 6;
    const int lane = tid & 63;
    const int gr   = blockIdx.x * 4 + wave;        // 0..16383

    if (blockIdx.x < 8) {                          // zero 8192 floats of out
        f32x4 z = {0.f, 0.f, 0.f, 0.f};
        ((f32x4*)out)[blockIdx.x * 256 + tid] = z;
    }

    const float* src; unsigned char* dst; int row;
    if (gr < NROWS) { src = Ex; dst = Xn; row = gr; }
    else            { src = Ey; dst = Yn; row = gr - NROWS; }

    const float4 v = *(const float4*)(src + (size_t)row * DDIM + lane * 4);
    float ss = v.x * v.x + v.y * v.y + v.z * v.z + v.w * v.w;
#pragma unroll
    for (int o = 32; o > 0; o >>= 1) ss += __shfl_xor(ss, o);
    const float inv = 1.0f / fmaxf(sqrtf(ss), 1e-8f);
    // pack 4 normalized floats -> 4 OCP e4m3 bytes
    int p = __builtin_amdgcn_cvt_pk_fp8_f32(v.x * inv, v.y * inv, 0, false);
    p     = __builtin_amdgcn_cvt_pk_fp8_f32(v.z * inv, v.w * inv, p, true);
    ((int*)(dst + (size_t)row * KB))[lane] = p;
}

__device__ inline void async_load16(const void* g, void* l) {
    __builtin_amdgcn_global_load_lds(
        (const __attribute__((address_space(1))) unsigned int*)g,
        (__attribute__((address_space(3))) unsigned int*)l, 16, 0, 0);
}

// C = Xn * Yn^T fused with gaussian + column-sum, MX-fp8 path.
// 128x128 tile, 4 waves 2x2, wave tile 64x64.  FULL K (256 fp8 bytes) staged
// in ONE round -> a single barrier pair per block (kills the 4x barrier-drain
// of the bf16 version).  mfma_scale_f32_16x16x128_f8f6f4, scales = 1.0 (0x7f).
// 16B k-chunks XOR-swizzled by (row&15): LDS[row][kc] = global chunk kc^(row&15).
__global__ __launch_bounds__(256, 2) void cosgauss_gemm(
    const unsigned char* __restrict__ Xn,
    const unsigned char* __restrict__ Yn,
    float* __restrict__ out) {
    __shared__ unsigned char As[TILE * KB];    // 32 KB
    __shared__ unsigned char Bs[TILE * KB];    // 32 KB
    __shared__ float colpart[TILE];

    const int tid  = threadIdx.x;
    const int lane = tid & 63;
    const int w    = tid >> 6;       // wave 0..3
    const int wr   = w >> 1;         // wave row 0..1 (64 rows each)
    const int wc   = w & 1;          // wave col 0..1 (64 cols each)
    const int rowBase = blockIdx.y * TILE;
    const int colBase = blockIdx.x * TILE;

    const unsigned char* Ag = Xn + (size_t)rowBase * KB;
    const unsigned char* Bg = Yn + (size_t)colBase * KB;

    // ---- stage whole K: 32 instr for A (4 rows each) + 32 for B, /4 waves
    const int lr = lane >> 4;        // sub-row 0..3 within 4-row group
    const int kc = lane & 15;        // 16B chunk this lane WRITES (forced)
#pragma unroll
    for (int j = 0; j < 8; ++j) {
        const int g = w * 8 + j;                 // 4-row group 0..31
        const int r = g * 4 + lr;
        const int kcS = kc ^ (r & 15);           // swizzled global chunk
        async_load16(Ag + (size_t)r * KB + kcS * 16, (char*)As + g * 1024);
        async_load16(Bg + (size_t)r * KB + kcS * 16, (char*)Bs + g * 1024);
    }
    __syncthreads();                 // drains vmcnt(0): the ONLY k-loop barrier

    // ---- compute: 2 k-steps of 16x16x128, 4x4 frags
    const int lm = lane & 15;        // m (A) / n (B) index; also swizzle key
    const int kq = lane >> 4;        // k-quad: 32 k-bytes = 2 chunks
    f32x4 acc[4][4] = {};

#pragma unroll
    for (int ks = 0; ks < 2; ++ks) {
        const int c0 = ks * 8 + kq * 2;
        i32x8 a[4], b[4];
#pragma unroll
        for (int rf = 0; rf < 4; ++rf) {
            const unsigned char* p = As + (wr * 64 + rf * 16 + lm) * KB;
            const i32x4 lo = *(const i32x4*)(p + ((c0    ) ^ lm) * 16);
            const i32x4 hi = *(const i32x4*)(p + ((c0 + 1) ^ lm) * 16);
            a[rf][0]=lo[0]; a[rf][1]=lo[1]; a[rf][2]=lo[2]; a[rf][3]=lo[3];
            a[rf][4]=hi[0]; a[rf][5]=hi[1]; a[rf][6]=hi[2]; a[rf][7]=hi[3];
        }
#pragma unroll
        for (int cf = 0; cf < 4; ++cf) {
            const unsigned char* p = Bs + (wc * 64 + cf * 16 + lm) * KB;
            const i32x4 lo = *(const i32x4*)(p + ((c0    ) ^ lm) * 16);
            const i32x4 hi = *(const i32x4*)(p + ((c0 + 1) ^ lm) * 16);
            b[cf][0]=lo[0]; b[cf][1]=lo[1]; b[cf][2]=lo[2]; b[cf][3]=lo[3];
            b[cf][4]=hi[0]; b[cf][5]=hi[1]; b[cf][6]=hi[2]; b[cf][7]=hi[3];
        }
#pragma unroll
        for (int rf = 0; rf < 4; ++rf)
#pragma unroll
            for (int cf = 0; cf < 4; ++cf)
                acc[rf][cf] = __builtin_amdgcn_mfma_scale_f32_16x16x128_f8f6f4(
                    a[rf], b[cf], acc[rf][cf], 0, 0, 0, 0x7f, 0, 0x7f);
    }

    // ---- epilogue: gaussian + column sums, with hard-zero skip.
    // exp2(f(c)) == 0.0f exactly whenever f(c) < -160; f monotone inc. in c.
    float cmax = -2.0f;
#pragma unroll
    for (int rf = 0; rf < 4; ++rf)
#pragma unroll
        for (int cf = 0; cf < 4; ++cf)
#pragma unroll
            for (int i = 0; i < 4; ++i)
                cmax = fmaxf(cmax, acc[rf][cf][i]);
    const bool need = fmaf(cmax, fmaf(cmax, PA, PB), PC) >= ZCUT;

    float s[4] = {0.f, 0.f, 0.f, 0.f};
    if (__any(need)) {               // ~0.1% of waves
#pragma unroll
        for (int cf = 0; cf < 4; ++cf) {
            float t = 0.0f;
#pragma unroll
            for (int rf = 0; rf < 4; ++rf) {
#pragma unroll
                for (int i = 0; i < 4; ++i) {
                    const float c = acc[rf][cf][i];
                    t += exp2f(fmaf(c, fmaf(c, PA, PB), PC));
                }
            }
            t += __shfl_xor(t, 16);  // reduce over the 4 row-quads
            t += __shfl_xor(t, 32);
            s[cf] = t;
        }
    }
    // C/D layout: col = lane&15, row = (lane>>4)*4 + reg  [m89/m91 verified]
    const float v = (lane < 16) ? s[0] : (lane < 32) ? s[1] : (lane < 48) ? s[2] : s[3];
    const int c = wc * 64 + lane;    // 0..127 within tile
    if (wr == 0) colpart[c] = v;
    __syncthreads();
    if (wr == 1) {
        const float tot = v + colpart[c];
        if (tot != 0.0f) atomicAdd(&out[colBase + c], tot);
    }
}

extern "C" void kernel_launch(void* const* d_in, const int* in_sizes, int n_in,
                              void* d_out, int out_size, void* d_ws, size_t ws_size,
                              hipStream_t stream) {
    const float* Ex = (const float*)d_in[0];
    const float* Ey = (const float*)d_in[1];
    float* out = (float*)d_out;

    unsigned char* Xn = (unsigned char*)d_ws;                  // 2 MB fp8
    unsigned char* Yn = Xn + (size_t)NROWS * KB;               // +2 MB

    normalize2<<<(2 * NROWS) / 4, 256, 0, stream>>>(Ex, Ey, Xn, Yn, out);

    dim3 grid(NROWS / TILE, NROWS / TILE);   // 64 x 64 tiles
    cosgauss_gemm<<<grid, 256, 0, stream>>>(Xn, Yn, out);
}